// Round 17
// baseline (163.644 us; speedup 1.0000x reference)
//
#include <hip/hip_runtime.h>
#include <stdint.h>

#define DIMF   1024
#define HEADS  16
#define HD     64
#define BB     2
#define NN     2048
#define NKP    2176   // 2049 keys padded to 17*128
#define NTILE  17     // 128-key tiles
#define NPHANT 127.0f // padded phantom keys (2049..2175), each contributes p=1

typedef __attribute__((ext_vector_type(8))) __bf16 bf16x8;
typedef __attribute__((ext_vector_type(4))) float  f32x4;

__device__ __forceinline__ float b2f(uint16_t h) {
  union { uint32_t u; float f; } v; v.u = ((uint32_t)h) << 16; return v.f;
}
__device__ __forceinline__ uint16_t f2b(float f) {
  union { float f; uint32_t u; } v; v.f = f;
  uint32_t r = v.u + 0x7FFFu + ((v.u >> 16) & 1u);
  return (uint16_t)(r >> 16);
}

// async global->LDS DMA, 16B per lane. LDS dest = wave-uniform base + lane*16.
__device__ __forceinline__ void gl_lds16(const void* g, void* l) {
  __builtin_amdgcn_global_load_lds(
      (const __attribute__((address_space(1))) void*)g,
      (__attribute__((address_space(3))) void*)l, 16, 0, 0);
}

// ---- merged preprocessing (single launch):
//   blocks [0,4096)      : cvt x (fp32) -> x_bf (bf16), float4 loads
//   blocks [4096,5120)   : void K/V row + zero padding (128 padded rows)
//   blocks [5120,8192)   : transpose wqkv 1024x3072 -> bf16 3072x1024
//   blocks [8192,9216)   : transpose wout 1024x1024 -> bf16 1024x1024
__global__ __launch_bounds__(256) void prep_k(const float* __restrict__ x,
                                              uint16_t* __restrict__ x_bf,
                                              const float* __restrict__ vk,
                                              const float* __restrict__ vv,
                                              uint16_t* __restrict__ k_ws,
                                              uint16_t* __restrict__ vt_ws,
                                              const float* __restrict__ wqkv,
                                              uint16_t* __restrict__ wqkvT,
                                              const float* __restrict__ wout,
                                              uint16_t* __restrict__ woutT) {
  __shared__ uint16_t tile[32][33];
  const int blk = blockIdx.x;
  if (blk < 4096) {
    int i = blk * 256 + threadIdx.x;             // < 1048576 float4s
    float4 v = *(const float4*)&x[(size_t)i * 4];
    uint16_t* d = x_bf + (size_t)i * 4;
    d[0] = f2b(v.x); d[1] = f2b(v.y); d[2] = f2b(v.z); d[3] = f2b(v.w);
  } else if (blk < 5120) {
    int idx = (blk - 4096) * 256 + threadIdx.x;  // 0 .. 262143
    int dd = idx & 63;
    int r  = (idx >> 6) & 127;     // padded key row 2048+r (r=0..127)
    int bh = idx >> 13;            // 0..31
    int h  = bh & (HEADS - 1);
    uint16_t kv  = (r == 0) ? f2b(vk[h * HD + dd]) : (uint16_t)0;
    uint16_t vvv = (r == 0) ? f2b(vv[h * HD + dd]) : (uint16_t)0;
    k_ws[((size_t)bh * NKP + NN + r) * HD + dd]  = kv;
    vt_ws[((size_t)bh * HD + dd) * NKP + NN + r] = vvv;
  } else {
    int tb = blk - 5120;
    const float* src; uint16_t* dst; int N, bx, by;
    if (tb < 3072) { src = wqkv; dst = wqkvT; N = 3072; bx = (tb % 96) * 32; by = (tb / 96) * 32; }
    else { tb -= 3072; src = wout; dst = woutT; N = 1024; bx = (tb % 32) * 32; by = (tb / 32) * 32; }
    const int M = 1024;
    int xx = threadIdx.x & 31, y0 = (threadIdx.x >> 5) * 4;
#pragma unroll
    for (int i = 0; i < 4; ++i)
      tile[y0 + i][xx] = f2b(src[(size_t)(by + y0 + i) * N + bx + xx]);
    __syncthreads();
#pragma unroll
    for (int i = 0; i < 4; ++i)
      dst[(size_t)(bx + y0 + i) * M + by + xx] = tile[xx][y0 + i];
  }
}

// ------------- GEMM0: C[M,N] = A[M,K] * Bt[N,K]^T, 128x128 tile, BK=64 -------------
// Scatter epilogue: bf16 Q [bh,2048,64] PRE-SCALED by per-head scale*log2e,
// K [bh,NKP,64], Vt [bh,64,NKP]
__global__ __launch_bounds__(256) void gemm0_k(const uint16_t* __restrict__ A,
                                               const uint16_t* __restrict__ Bt,
                                               int K,
                                               uint16_t* __restrict__ o0,
                                               uint16_t* __restrict__ o1,
                                               uint16_t* __restrict__ o2,
                                               const float* __restrict__ trace,
                                               const float* __restrict__ factor) {
  __shared__ uint16_t lds_a[128][64];   // 16 KB, linear dest for global_load_lds
  __shared__ uint16_t lds_b[128][64];   // 16 KB
  const int m0 = blockIdx.y * 128, n0 = blockIdx.x * 128;
  const int tid = threadIdx.x, lane = tid & 63, wid = tid >> 6;
  const int wm = (wid >> 1) * 64, wn = (wid & 1) * 64;
  const int lr = lane & 15, lg = lane >> 4;

  const int rsw = (lr & 7) << 4;
  const int rc0 = (lg * 16) ^ rsw;
  const int rc1 = (64 + lg * 16) ^ rsw;

  f32x4 acc[4][4] = {};
  for (int k0 = 0; k0 < K; k0 += 64) {
    __syncthreads();
#pragma unroll
    for (int it = 0; it < 4; ++it) {
      const int chunk = wid * 4 + it;            // 0..15 (1 KiB each)
      const int o = chunk * 1024 + lane * 16;
      const int r = o >> 7, cb = o & 127;        // 128 B per row
      const int scb = cb ^ ((r & 7) << 4);       // pre-swizzled source col
      gl_lds16((const char*)&A[(size_t)(m0 + r) * K + k0] + scb,
               (char*)&lds_a[0][0] + chunk * 1024);
      gl_lds16((const char*)&Bt[(size_t)(n0 + r) * K + k0] + scb,
               (char*)&lds_b[0][0] + chunk * 1024);
    }
    __syncthreads();
    bf16x8 af[4][2], bf[4][2];
#pragma unroll
    for (int i = 0; i < 4; ++i) {
      const char* ra = (const char*)&lds_a[0][0] + (wm + i * 16 + lr) * 128;
      af[i][0] = *(const bf16x8*)(ra + rc0);
      af[i][1] = *(const bf16x8*)(ra + rc1);
    }
#pragma unroll
    for (int j = 0; j < 4; ++j) {
      const char* rb = (const char*)&lds_b[0][0] + (wn + j * 16 + lr) * 128;
      bf[j][0] = *(const bf16x8*)(rb + rc0);
      bf[j][1] = *(const bf16x8*)(rb + rc1);
    }
#pragma unroll
    for (int kk = 0; kk < 2; ++kk)
#pragma unroll
      for (int i = 0; i < 4; ++i)
#pragma unroll
        for (int j = 0; j < 4; ++j)
          acc[i][j] = __builtin_amdgcn_mfma_f32_16x16x32_bf16(af[i][kk], bf[j][kk],
                                                              acc[i][j], 0, 0, 0);
  }
#pragma unroll
  for (int i = 0; i < 4; ++i)
#pragma unroll
    for (int j = 0; j < 4; ++j)
#pragma unroll
      for (int r = 0; r < 4; ++r) {
        int mg = m0 + wm + i * 16 + lg * 4 + r;   // C row = m (m89 layout)
        int ng = n0 + wn + j * 16 + lr;            // C col = n
        int b = mg >> 11, n = mg & (NN - 1);
        int which = ng >> 10, rem = ng & (DIMF - 1), h = rem >> 6, dd = rem & 63;
        int bh = b * HEADS + h;
        float v = acc[i][j][r];
        if (which == 0) {   // Q: fold (dim^-0.5 / temp) * log2(e) into Q
          float tmp = fmaxf(1.0f + fabsf(trace[h]) * factor[h], 1.0f);
          v *= 0.04508422f / tmp;                  // 0.03125 * 1.44269504
        }
        uint16_t bv = f2b(v);
        if (which == 0)      o0[((size_t)bh * NN + n) * HD + dd] = bv;
        else if (which == 1) o1[((size_t)bh * NKP + n) * HD + dd] = bv;
        else                 o2[((size_t)bh * HD + dd) * NKP + n] = bv;  // V transposed
      }
}

// ------------- GEMM1: out[M,1024] = A[M,K] * Bt[1024,K]^T + bias, FP32 out -------------
__global__ __launch_bounds__(256) void gemm1_k(const uint16_t* __restrict__ A,
                                               const uint16_t* __restrict__ Bt,
                                               int K,
                                               float* __restrict__ fo,
                                               const float* __restrict__ bias) {
  __shared__ uint16_t lds_a[64][64];    // 8 KB
  __shared__ uint16_t lds_b[128][64];   // 16 KB
  const int m0 = blockIdx.y * 64, n0 = blockIdx.x * 128;
  const int tid = threadIdx.x, lane = tid & 63, wid = tid >> 6;
  const int wm = (wid >> 1) * 32, wn = (wid & 1) * 64;
  const int lr = lane & 15, lg = lane >> 4;

  const int rsw = (lr & 7) << 4;
  const int rc0 = (lg * 16) ^ rsw;
  const int rc1 = (64 + lg * 16) ^ rsw;

  f32x4 acc[2][4] = {};
  for (int k0 = 0; k0 < K; k0 += 64) {
    __syncthreads();
#pragma unroll
    for (int it = 0; it < 6; ++it) {
      const int c = wid * 6 + it;                // 0..23 (1 KiB each): 8 A + 16 B
      if (c < 8) {
        const int o = c * 1024 + lane * 16;
        const int r = o >> 7, cb = o & 127;
        const int scb = cb ^ ((r & 7) << 4);
        gl_lds16((const char*)&A[(size_t)(m0 + r) * K + k0] + scb,
                 (char*)&lds_a[0][0] + c * 1024);
      } else {
        const int o2 = (c - 8) * 1024 + lane * 16;
        const int r = o2 >> 7, cb = o2 & 127;
        const int scb = cb ^ ((r & 7) << 4);
        gl_lds16((const char*)&Bt[(size_t)(n0 + r) * K + k0] + scb,
                 (char*)&lds_b[0][0] + (c - 8) * 1024);
      }
    }
    __syncthreads();
    bf16x8 af[2][2], bf[4][2];
#pragma unroll
    for (int i = 0; i < 2; ++i) {
      const char* ra = (const char*)&lds_a[0][0] + (wm + i * 16 + lr) * 128;
      af[i][0] = *(const bf16x8*)(ra + rc0);
      af[i][1] = *(const bf16x8*)(ra + rc1);
    }
#pragma unroll
    for (int j = 0; j < 4; ++j) {
      const char* rb = (const char*)&lds_b[0][0] + (wn + j * 16 + lr) * 128;
      bf[j][0] = *(const bf16x8*)(rb + rc0);
      bf[j][1] = *(const bf16x8*)(rb + rc1);
    }
#pragma unroll
    for (int kk = 0; kk < 2; ++kk)
#pragma unroll
      for (int i = 0; i < 2; ++i)
#pragma unroll
        for (int j = 0; j < 4; ++j)
          acc[i][j] = __builtin_amdgcn_mfma_f32_16x16x32_bf16(af[i][kk], bf[j][kk],
                                                              acc[i][j], 0, 0, 0);
  }
#pragma unroll
  for (int i = 0; i < 2; ++i)
#pragma unroll
    for (int j = 0; j < 4; ++j)
#pragma unroll
      for (int r = 0; r < 4; ++r) {
        int mg = m0 + wm + i * 16 + lg * 4 + r;
        int ng = n0 + wn + j * 16 + lr;
        fo[(size_t)mg * DIMF + ng] = acc[i][j][r] + bias[ng];
      }
}

// ---- flash attention: round-14 structure, KVBLK=128 (halved barriers) + exp2 Q ----
// 8 waves x 16 q-rows; 128-key tiles staged via global_load_lds (32 KB/tile),
// XOR-swizzled reads; LDS 66 KB -> still 2 blocks/CU (grid-limited). Q arrives
// PRE-SCALED by scale*log2e -> p = exp2f(s) (bare v_exp_f32). Phantom keys
// (2049..2175) are zero -> p=1, subtract 127 at the end. bh-fastest grid.
__global__ __launch_bounds__(512) void attn_k(const uint16_t* __restrict__ q_ws,
                                              const uint16_t* __restrict__ k_ws,
                                              const uint16_t* __restrict__ vt_ws,
                                              uint16_t* __restrict__ o_ws) {
  __shared__ uint16_t ldsk[128][64];      // [key][d], 128 B rows, swizzled cols (16 KB)
  __shared__ uint16_t ldsv[64][128];      // [d][key], 256 B rows, swizzled cols (16 KB)
  __shared__ uint16_t ldsp[8][16][136];   // [wave][q][key(+8 pad)] (34 KB)
  const int bh = blockIdx.x;              // FASTEST dim -> XCD = bh%8 (L2 locality)
  const int qb = blockIdx.y;
  const int h = bh & (HEADS - 1), b = bh >> 4;
  const int tid = threadIdx.x, lane = tid & 63, wid = tid >> 6;  // wid 0..7
  const int lr = lane & 15, lg = lane >> 4;

  const int qrow0 = qb * 128 + wid * 16;
  const uint16_t* qrow = q_ws + ((size_t)bh * NN + qrow0 + lr) * HD;
  bf16x8 qf[2];
  qf[0] = *(const bf16x8*)(qrow + lg * 8);
  qf[1] = *(const bf16x8*)(qrow + 32 + lg * 8);

  // hoisted loop-invariant LDS read addresses (row low-3-bits == lr&7)
  const int rsw = (lr & 7) << 4;
  const char* kb0 = (const char*)&ldsk[0][0] + lr * 128 + ((lg * 16) ^ rsw);
  const char* kb1 = (const char*)&ldsk[0][0] + lr * 128 + ((64 + lg * 16) ^ rsw);
  const char* vbs = (const char*)&ldsv[0][0] + lr * 256;
  int voff[4];
#pragma unroll
  for (int kk = 0; kk < 4; ++kk) voff[kk] = (kk * 64 + lg * 16) ^ rsw;
  const char* pr = (const char*)&ldsp[wid][lr][lg * 8];

  f32x4 acc[4] = {};
  float lsum[4] = {0.f, 0.f, 0.f, 0.f};

  for (int t = 0; t < NTILE; ++t) {
    const int t0 = t * 128;
    __syncthreads();
#pragma unroll
    for (int it = 0; it < 2; ++it) {
      const int chunk = wid * 2 + it;           // 0..15 (1 KiB each)
      const int o = chunk * 1024 + lane * 16;
      // K: [128 keys][64 d] = 128 B rows
      { const int r = o >> 7, cb = o & 127;
        const int scb = cb ^ ((r & 7) << 4);
        gl_lds16((const char*)&k_ws[((size_t)bh * NKP + t0 + r) * HD] + scb,
                 (char*)&ldsk[0][0] + chunk * 1024); }
      // V: [64 d][128 keys] = 256 B rows
      { const int r = o >> 8, cb = o & 255;
        const int scb = cb ^ ((r & 7) << 4);
        gl_lds16((const char*)&vt_ws[((size_t)bh * HD + r) * NKP + t0] + scb,
                 (char*)&ldsv[0][0] + chunk * 1024); }
    }
    __syncthreads();

    // S = Q K^T (8 chunks of 16 keys); p = exp2(s) (Q pre-scaled); stage P
#pragma unroll
    for (int c = 0; c < 8; ++c) {
      bf16x8 kf0 = *(const bf16x8*)(kb0 + c * 2048);
      bf16x8 kf1 = *(const bf16x8*)(kb1 + c * 2048);
      f32x4 sa = {};
      __builtin_amdgcn_s_setprio(1);
      sa = __builtin_amdgcn_mfma_f32_16x16x32_bf16(qf[0], kf0, sa, 0, 0, 0);
      sa = __builtin_amdgcn_mfma_f32_16x16x32_bf16(qf[1], kf1, sa, 0, 0, 0);
      __builtin_amdgcn_s_setprio(0);
#pragma unroll
      for (int r = 0; r < 4; ++r) {
        union { float f; uint32_t u; } pv;
        pv.f = exp2f(sa[r]);
        ldsp[wid][lg * 4 + r][c * 16 + lr] = (uint16_t)(pv.u >> 16);
        pv.u &= 0xffff0000u;
        lsum[r] += pv.f;
      }
    }
    // ordering fence: scalar u16 writes -> vector bf16x8 read, same wave
    asm volatile("" ::: "memory");
    __builtin_amdgcn_sched_barrier(0);
    // O += P V  (4 k-steps of 32 keys)
    __builtin_amdgcn_s_setprio(1);
#pragma unroll
    for (int kk = 0; kk < 4; ++kk) {
      bf16x8 pf = *(const bf16x8*)(pr + kk * 64);
#pragma unroll
      for (int cd = 0; cd < 4; ++cd) {
        bf16x8 vf = *(const bf16x8*)(vbs + cd * 4096 + voff[kk]);
        acc[cd] = __builtin_amdgcn_mfma_f32_16x16x32_bf16(pf, vf, acc[cd], 0, 0, 0);
      }
    }
    __builtin_amdgcn_s_setprio(0);
  }
  // final l reduce (16-lane groups), drop phantom keys, normalize, write O
#pragma unroll
  for (int r = 0; r < 4; ++r) {
    float l = lsum[r];
    l += __shfl_xor(l, 1); l += __shfl_xor(l, 2);
    l += __shfl_xor(l, 4); l += __shfl_xor(l, 8);
    l -= NPHANT;
    const float inv = 1.0f / l;
    const int n = qrow0 + lg * 4 + r;
    size_t base = ((size_t)b * NN + n) * DIMF + h * HD;
#pragma unroll
    for (int cd = 0; cd < 4; ++cd)
      o_ws[base + cd * 16 + lr] = f2b(acc[cd][r] * inv);
  }
}

extern "C" void kernel_launch(void* const* d_in, const int* in_sizes, int n_in,
                              void* d_out, int out_size, void* d_ws, size_t ws_size,
                              hipStream_t stream) {
  const float* x      = (const float*)d_in[0];
  const float* wqkv   = (const float*)d_in[1];
  const float* wout   = (const float*)d_in[2];
  const float* bout   = (const float*)d_in[3];
  // d_in[4] = void_q: unused (void query row is dropped by the reference)
  const float* voidk  = (const float*)d_in[5];
  const float* voidv  = (const float*)d_in[6];
  const float* trace  = (const float*)d_in[7];
  const float* factor = (const float*)d_in[8];
  float* out = (float*)d_out;           // reference output dtype is FP32

  uint16_t* ws    = (uint16_t*)d_ws;
  uint16_t* x_bf  = ws;                       // 2*2048*1024  = 4,194,304 elems
  uint16_t* o_ws  = x_bf;                     // ALIAS: x_bf dead after gemm0
  uint16_t* wqkvT = x_bf  + 4194304;          // 3072*1024    = 3,145,728
  uint16_t* woutT = wqkvT + 3145728;          // 1024*1024    = 1,048,576
  uint16_t* q_ws  = woutT + 1048576;          // 2*16*2048*64 = 4,194,304
  uint16_t* k_ws  = q_ws  + 4194304;          // 2*16*2176*64 = 4,456,448
  uint16_t* vt_ws = k_ws  + 4456448;          // 4,456,448   (total ~43 MB)

  prep_k<<<dim3(9216), dim3(256), 0, stream>>>(x, x_bf, voidk, voidv, k_ws, vt_ws,
                                               wqkv, wqkvT, wout, woutT);
  gemm0_k<<<dim3(3072 / 128, 4096 / 128), dim3(256), 0, stream>>>(
      x_bf, wqkvT, 1024, q_ws, k_ws, vt_ws, trace, factor);
  attn_k<<<dim3(HEADS * BB, NN / 128), dim3(512), 0, stream>>>(
      q_ws, k_ws, vt_ws, o_ws);
  gemm1_k<<<dim3(1024 / 128, 4096 / 64), dim3(256), 0, stream>>>(
      o_ws, woutT, 1024, out, bout);
}

// Round 18
// 130.336 us; speedup vs baseline: 1.2556x; 1.2556x over previous
//
#include <hip/hip_runtime.h>
#include <stdint.h>

#define DIMF   1024
#define HEADS  16
#define HD     64
#define BB     2
#define NN     2048
#define NKP    2112   // 2049 keys padded to 33*64
#define NTILE  33

typedef __attribute__((ext_vector_type(8))) __bf16 bf16x8;
typedef __attribute__((ext_vector_type(4))) float  f32x4;

__device__ __forceinline__ float b2f(uint16_t h) {
  union { uint32_t u; float f; } v; v.u = ((uint32_t)h) << 16; return v.f;
}
__device__ __forceinline__ uint16_t f2b(float f) {
  union { float f; uint32_t u; } v; v.f = f;
  uint32_t r = v.u + 0x7FFFu + ((v.u >> 16) & 1u);
  return (uint16_t)(r >> 16);
}

// async global->LDS DMA, 16B per lane. LDS dest = wave-uniform base + lane*16.
__device__ __forceinline__ void gl_lds16(const void* g, void* l) {
  __builtin_amdgcn_global_load_lds(
      (const __attribute__((address_space(1))) void*)g,
      (__attribute__((address_space(3))) void*)l, 16, 0, 0);
}

// ---- merged preprocessing (single launch) — EXACT round-16 kernel ----
__global__ __launch_bounds__(256) void prep_k(const float* __restrict__ x,
                                              uint16_t* __restrict__ x_bf,
                                              const float* __restrict__ vk,
                                              const float* __restrict__ vv,
                                              uint16_t* __restrict__ k_ws,
                                              uint16_t* __restrict__ vt_ws,
                                              const float* __restrict__ wqkv,
                                              uint16_t* __restrict__ wqkvT,
                                              const float* __restrict__ wout,
                                              uint16_t* __restrict__ woutT) {
  __shared__ uint16_t tile[32][33];
  const int blk = blockIdx.x;
  if (blk < 4096) {
    int i = blk * 256 + threadIdx.x;             // < 1048576 float4s
    float4 v = *(const float4*)&x[(size_t)i * 4];
    uint16_t* d = x_bf + (size_t)i * 4;
    d[0] = f2b(v.x); d[1] = f2b(v.y); d[2] = f2b(v.z); d[3] = f2b(v.w);
  } else if (blk < 4608) {
    int idx = (blk - 4096) * 256 + threadIdx.x;  // 0 .. 131071
    int dd = idx & 63;
    int r  = (idx >> 6) & 63;      // padded key row 2048+r
    int bh = idx >> 12;            // 0..31
    int h  = bh & (HEADS - 1);
    uint16_t kv  = (r == 0) ? f2b(vk[h * HD + dd]) : (uint16_t)0;
    uint16_t vvv = (r == 0) ? f2b(vv[h * HD + dd]) : (uint16_t)0;
    k_ws[((size_t)bh * NKP + NN + r) * HD + dd]  = kv;
    vt_ws[((size_t)bh * HD + dd) * NKP + NN + r] = vvv;
  } else {
    int tb = blk - 4608;
    const float* src; uint16_t* dst; int N, bx, by;
    if (tb < 3072) { src = wqkv; dst = wqkvT; N = 3072; bx = (tb % 96) * 32; by = (tb / 96) * 32; }
    else { tb -= 3072; src = wout; dst = woutT; N = 1024; bx = (tb % 32) * 32; by = (tb / 32) * 32; }
    const int M = 1024;
    int xx = threadIdx.x & 31, y0 = (threadIdx.x >> 5) * 4;
#pragma unroll
    for (int i = 0; i < 4; ++i)
      tile[y0 + i][xx] = f2b(src[(size_t)(by + y0 + i) * N + bx + xx]);
    __syncthreads();
#pragma unroll
    for (int i = 0; i < 4; ++i)
      dst[(size_t)(bx + y0 + i) * M + by + xx] = tile[xx][y0 + i];
  }
}

// ------------- GEMM0 — EXACT round-16 kernel (128x128, BK=64, swizzled) -------------
__global__ __launch_bounds__(256) void gemm0_k(const uint16_t* __restrict__ A,
                                               const uint16_t* __restrict__ Bt,
                                               int K,
                                               uint16_t* __restrict__ o0,
                                               uint16_t* __restrict__ o1,
                                               uint16_t* __restrict__ o2) {
  __shared__ uint16_t lds_a[128][64];   // 16 KB, linear dest for global_load_lds
  __shared__ uint16_t lds_b[128][64];   // 16 KB
  const int m0 = blockIdx.y * 128, n0 = blockIdx.x * 128;
  const int tid = threadIdx.x, lane = tid & 63, wid = tid >> 6;
  const int wm = (wid >> 1) * 64, wn = (wid & 1) * 64;
  const int lr = lane & 15, lg = lane >> 4;

  const int rsw = (lr & 7) << 4;
  const int rc0 = (lg * 16) ^ rsw;
  const int rc1 = (64 + lg * 16) ^ rsw;

  f32x4 acc[4][4] = {};
  for (int k0 = 0; k0 < K; k0 += 64) {
    __syncthreads();
#pragma unroll
    for (int it = 0; it < 4; ++it) {
      const int chunk = wid * 4 + it;            // 0..15 (1 KiB each)
      const int o = chunk * 1024 + lane * 16;
      const int r = o >> 7, cb = o & 127;        // 128 B per row
      const int scb = cb ^ ((r & 7) << 4);       // pre-swizzled source col
      gl_lds16((const char*)&A[(size_t)(m0 + r) * K + k0] + scb,
               (char*)&lds_a[0][0] + chunk * 1024);
      gl_lds16((const char*)&Bt[(size_t)(n0 + r) * K + k0] + scb,
               (char*)&lds_b[0][0] + chunk * 1024);
    }
    __syncthreads();
    bf16x8 af[4][2], bf[4][2];
#pragma unroll
    for (int i = 0; i < 4; ++i) {
      const char* ra = (const char*)&lds_a[0][0] + (wm + i * 16 + lr) * 128;
      af[i][0] = *(const bf16x8*)(ra + rc0);
      af[i][1] = *(const bf16x8*)(ra + rc1);
    }
#pragma unroll
    for (int j = 0; j < 4; ++j) {
      const char* rb = (const char*)&lds_b[0][0] + (wn + j * 16 + lr) * 128;
      bf[j][0] = *(const bf16x8*)(rb + rc0);
      bf[j][1] = *(const bf16x8*)(rb + rc1);
    }
#pragma unroll
    for (int kk = 0; kk < 2; ++kk)
#pragma unroll
      for (int i = 0; i < 4; ++i)
#pragma unroll
        for (int j = 0; j < 4; ++j)
          acc[i][j] = __builtin_amdgcn_mfma_f32_16x16x32_bf16(af[i][kk], bf[j][kk],
                                                              acc[i][j], 0, 0, 0);
  }
#pragma unroll
  for (int i = 0; i < 4; ++i)
#pragma unroll
    for (int j = 0; j < 4; ++j)
#pragma unroll
      for (int r = 0; r < 4; ++r) {
        int mg = m0 + wm + i * 16 + lg * 4 + r;   // C row = m (m89 layout)
        int ng = n0 + wn + j * 16 + lr;            // C col = n
        int b = mg >> 11, n = mg & (NN - 1);
        int which = ng >> 10, rem = ng & (DIMF - 1), h = rem >> 6, dd = rem & 63;
        int bh = b * HEADS + h;
        uint16_t bv = f2b(acc[i][j][r]);
        if (which == 0)      o0[((size_t)bh * NN + n) * HD + dd] = bv;
        else if (which == 1) o1[((size_t)bh * NKP + n) * HD + dd] = bv;
        else                 o2[((size_t)bh * HD + dd) * NKP + n] = bv;  // V transposed
      }
}

// ------------- GEMM1 — EXACT round-16 kernel (BM=64, BN=128) -------------
__global__ __launch_bounds__(256) void gemm1_k(const uint16_t* __restrict__ A,
                                               const uint16_t* __restrict__ Bt,
                                               int K,
                                               float* __restrict__ fo,
                                               const float* __restrict__ bias) {
  __shared__ uint16_t lds_a[64][64];    // 8 KB
  __shared__ uint16_t lds_b[128][64];   // 16 KB
  const int m0 = blockIdx.y * 64, n0 = blockIdx.x * 128;
  const int tid = threadIdx.x, lane = tid & 63, wid = tid >> 6;
  const int wm = (wid >> 1) * 32, wn = (wid & 1) * 64;
  const int lr = lane & 15, lg = lane >> 4;

  const int rsw = (lr & 7) << 4;
  const int rc0 = (lg * 16) ^ rsw;
  const int rc1 = (64 + lg * 16) ^ rsw;

  f32x4 acc[2][4] = {};
  for (int k0 = 0; k0 < K; k0 += 64) {
    __syncthreads();
#pragma unroll
    for (int it = 0; it < 6; ++it) {
      const int c = wid * 6 + it;                // 0..23 (1 KiB each): 8 A + 16 B
      if (c < 8) {
        const int o = c * 1024 + lane * 16;
        const int r = o >> 7, cb = o & 127;
        const int scb = cb ^ ((r & 7) << 4);
        gl_lds16((const char*)&A[(size_t)(m0 + r) * K + k0] + scb,
                 (char*)&lds_a[0][0] + c * 1024);
      } else {
        const int o2 = (c - 8) * 1024 + lane * 16;
        const int r = o2 >> 7, cb = o2 & 127;
        const int scb = cb ^ ((r & 7) << 4);
        gl_lds16((const char*)&Bt[(size_t)(n0 + r) * K + k0] + scb,
                 (char*)&lds_b[0][0] + (c - 8) * 1024);
      }
    }
    __syncthreads();
    bf16x8 af[2][2], bf[4][2];
#pragma unroll
    for (int i = 0; i < 2; ++i) {
      const char* ra = (const char*)&lds_a[0][0] + (wm + i * 16 + lr) * 128;
      af[i][0] = *(const bf16x8*)(ra + rc0);
      af[i][1] = *(const bf16x8*)(ra + rc1);
    }
#pragma unroll
    for (int j = 0; j < 4; ++j) {
      const char* rb = (const char*)&lds_b[0][0] + (wn + j * 16 + lr) * 128;
      bf[j][0] = *(const bf16x8*)(rb + rc0);
      bf[j][1] = *(const bf16x8*)(rb + rc1);
    }
#pragma unroll
    for (int kk = 0; kk < 2; ++kk)
#pragma unroll
      for (int i = 0; i < 2; ++i)
#pragma unroll
        for (int j = 0; j < 4; ++j)
          acc[i][j] = __builtin_amdgcn_mfma_f32_16x16x32_bf16(af[i][kk], bf[j][kk],
                                                              acc[i][j], 0, 0, 0);
  }
#pragma unroll
  for (int i = 0; i < 2; ++i)
#pragma unroll
    for (int j = 0; j < 4; ++j)
#pragma unroll
      for (int r = 0; r < 4; ++r) {
        int mg = m0 + wm + i * 16 + lg * 4 + r;
        int ng = n0 + wn + j * 16 + lr;
        fo[(size_t)mg * DIMF + ng] = acc[i][j][r] + bias[ng];
      }
}

// ---- flash attention: round-16 8-wave kernel + K/V DOUBLE-BUFFER stage-ahead ----
// The ONE change vs round 16: ldsk/ldsv are [2] buffers; STAGE(t+1) is issued
// BEFORE computing tile t; ONE barrier per tile (after compute) both drains the
// DMA (which had the full compute phase to land) and protects the buf/ldsp WAR.
// Occupancy unchanged: grid 512 = 2 blocks/CU (grid-limited), LDS 51 KB still
// allows 3. Everything else (fragment maps, swizzle, truncated-P softmax,
// setprio, bh-fastest grid) is byte-identical to round 16.
__global__ __launch_bounds__(512) void attn_k(const uint16_t* __restrict__ q_ws,
                                              const uint16_t* __restrict__ k_ws,
                                              const uint16_t* __restrict__ vt_ws,
                                              const float* __restrict__ trace,
                                              const float* __restrict__ factor,
                                              uint16_t* __restrict__ o_ws) {
  __shared__ uint16_t ldsk[2][64][64];   // [buf][key][d], swizzled cols (16 KB)
  __shared__ uint16_t ldsv[2][64][64];   // [buf][d][key], swizzled cols (16 KB)
  __shared__ uint16_t ldsp[8][16][72];   // per-wave P re-layout buffer (18.4 KB)
  const int bh = blockIdx.x;             // FASTEST dim -> XCD = bh%8 (L2 locality)
  const int qb = blockIdx.y;
  const int h = bh & (HEADS - 1), b = bh >> 4;
  const int tid = threadIdx.x, lane = tid & 63, wid = tid >> 6;  // wid 0..7
  const int lr = lane & 15, lg = lane >> 4;

  const float temp  = fmaxf(1.0f + fabsf(trace[h]) * factor[h], 1.0f);
  const float scale = 0.03125f / temp;   // dim^-0.5 / temperature

  const int qrow0 = qb * 128 + wid * 16;
  const uint16_t* qrow = q_ws + ((size_t)bh * NN + qrow0 + lr) * HD;
  bf16x8 qf[2];
  qf[0] = *(const bf16x8*)(qrow + lg * 8);
  qf[1] = *(const bf16x8*)(qrow + 32 + lg * 8);

  // hoisted loop-invariant LDS read offsets (row = c*16+lr -> row&7 == lr&7)
  const int rsw = (lr & 7) << 4;
  const int kb0 = lr * 128 + ((lg * 16) ^ rsw);
  const int kb1 = lr * 128 + ((64 + lg * 16) ^ rsw);
  const char* kbase = (const char*)&ldsk[0][0][0];
  const char* vbase = (const char*)&ldsv[0][0][0];
  const char* pr = (const char*)&ldsp[wid][lr][lg * 8];

  f32x4 acc[4] = {};
  float lsum[4] = {0.f, 0.f, 0.f, 0.f};

#define STAGE(buf, t)                                                            \
  {                                                                              \
    const int t0_ = (t) * 64;                                                    \
    const int chunk = wid;                    /* 0..7 (1 KiB each) */            \
    const int o = chunk * 1024 + lane * 16;                                      \
    const int r = o >> 7, cb = o & 127;       /* 128 B per row */                \
    const int scb = cb ^ ((r & 7) << 4);      /* pre-swizzled source col */      \
    gl_lds16((const char*)&k_ws[((size_t)bh * NKP + t0_ + r) * HD] + scb,        \
             (char*)&ldsk[buf][0][0] + chunk * 1024);                            \
    gl_lds16((const char*)&vt_ws[((size_t)bh * HD + r) * NKP + t0_] + scb,       \
             (char*)&ldsv[buf][0][0] + chunk * 1024);                            \
  }

  STAGE(0, 0);
  __syncthreads();   // vmcnt(0) drained: tile 0 visible
  int cur = 0;

  for (int t = 0; t < NTILE; ++t) {
    const int tn = (t + 1 < NTILE) ? t + 1 : t;  // last iter: harmless restage
    STAGE(cur ^ 1, tn);                          // issue BEFORE compute

    const int koff = cur * 8192;                 // byte offset of current buffer

    // S = Q K^T (4 chunks of 16 keys)
    f32x4 s[4];
#pragma unroll
    for (int c = 0; c < 4; ++c) {
      bf16x8 kf0 = *(const bf16x8*)(kbase + koff + kb0 + c * 2048);
      bf16x8 kf1 = *(const bf16x8*)(kbase + koff + kb1 + c * 2048);
      f32x4 sa = {};
      __builtin_amdgcn_s_setprio(1);
      sa = __builtin_amdgcn_mfma_f32_16x16x32_bf16(qf[0], kf0, sa, 0, 0, 0);
      sa = __builtin_amdgcn_mfma_f32_16x16x32_bf16(qf[1], kf1, sa, 0, 0, 0);
      __builtin_amdgcn_s_setprio(0);
      s[c] = sa;
    }
    // p = exp(s*scale), TRUNCATED to bf16; l accumulates the truncated value
#pragma unroll
    for (int c = 0; c < 4; ++c)
#pragma unroll
      for (int r = 0; r < 4; ++r) {
        union { float f; uint32_t u; } pv;
        pv.f = __expf(s[c][r] * scale);
        ldsp[wid][lg * 4 + r][c * 16 + lr] = (uint16_t)(pv.u >> 16);
        pv.u &= 0xffff0000u;
        lsum[r] += pv.f;
      }
    // ordering fence: scalar u16 writes -> vector bf16x8 read, same wave
    asm volatile("" ::: "memory");
    __builtin_amdgcn_sched_barrier(0);
    // O += P V
    __builtin_amdgcn_s_setprio(1);
#pragma unroll
    for (int kk = 0; kk < 2; ++kk) {
      bf16x8 pf = *(const bf16x8*)(pr + kk * 64);
#pragma unroll
      for (int cd = 0; cd < 4; ++cd) {
        bf16x8 vf = *(const bf16x8*)(vbase + koff + (kk ? kb1 : kb0) + cd * 2048);
        acc[cd] = __builtin_amdgcn_mfma_f32_16x16x32_bf16(pf, vf, acc[cd], 0, 0, 0);
      }
    }
    __builtin_amdgcn_s_setprio(0);
    __syncthreads();   // next tile landed (had full compute to arrive);
    cur ^= 1;          // buf & ldsp WAR protected
  }
  // final l reduce (16-lane groups), drop the 63 phantom keys, normalize, write O
#pragma unroll
  for (int r = 0; r < 4; ++r) {
    float l = lsum[r];
    l += __shfl_xor(l, 1); l += __shfl_xor(l, 2);
    l += __shfl_xor(l, 4); l += __shfl_xor(l, 8);
    l -= 63.0f;
    const float inv = 1.0f / l;
    const int n = qrow0 + lg * 4 + r;
    size_t base = ((size_t)b * NN + n) * DIMF + h * HD;
#pragma unroll
    for (int cd = 0; cd < 4; ++cd)
      o_ws[base + cd * 16 + lr] = f2b(acc[cd][r] * inv);
  }
}

extern "C" void kernel_launch(void* const* d_in, const int* in_sizes, int n_in,
                              void* d_out, int out_size, void* d_ws, size_t ws_size,
                              hipStream_t stream) {
  const float* x      = (const float*)d_in[0];
  const float* wqkv   = (const float*)d_in[1];
  const float* wout   = (const float*)d_in[2];
  const float* bout   = (const float*)d_in[3];
  // d_in[4] = void_q: unused (void query row is dropped by the reference)
  const float* voidk  = (const float*)d_in[5];
  const float* voidv  = (const float*)d_in[6];
  const float* trace  = (const float*)d_in[7];
  const float* factor = (const float*)d_in[8];
  float* out = (float*)d_out;           // reference output dtype is FP32

  uint16_t* ws    = (uint16_t*)d_ws;
  uint16_t* x_bf  = ws;                       // 2*2048*1024  = 4,194,304 elems
  uint16_t* o_ws  = x_bf;                     // ALIAS: x_bf dead after gemm0
  uint16_t* wqkvT = x_bf  + 4194304;          // 3072*1024    = 3,145,728
  uint16_t* woutT = wqkvT + 3145728;          // 1024*1024    = 1,048,576
  uint16_t* q_ws  = woutT + 1048576;          // 2*16*2048*64 = 4,194,304
  uint16_t* k_ws  = q_ws  + 4194304;          // 2*16*2112*64 = 4,325,376
  uint16_t* vt_ws = k_ws  + 4325376;          // 4,325,376   (total ~42.5 MB)

  prep_k<<<dim3(8704), dim3(256), 0, stream>>>(x, x_bf, voidk, voidv, k_ws, vt_ws,
                                               wqkv, wqkvT, wout, woutT);
  gemm0_k<<<dim3(3072 / 128, 4096 / 128), dim3(256), 0, stream>>>(
      x_bf, wqkvT, 1024, q_ws, k_ws, vt_ws);
  attn_k<<<dim3(HEADS * BB, NN / 128), dim3(512), 0, stream>>>(
      q_ws, k_ws, vt_ws, trace, factor, o_ws);
  gemm1_k<<<dim3(1024 / 128, 4096 / 64), dim3(256), 0, stream>>>(
      o_ws, woutT, 1024, out, bout);
}